// Round 6
// baseline (244.263 us; speedup 1.0000x reference)
//
#include <hip/hip_runtime.h>
#include <hip/hip_bf16.h>
#include <stdint.h>

#define BROWS 32768
#define LATENT 1024
#define HID 512

typedef float f32x4 __attribute__((ext_vector_type(4)));
typedef __bf16 bf16x8 __attribute__((ext_vector_type(8)));
typedef unsigned short us8 __attribute__((ext_vector_type(8)));

__device__ __forceinline__ void gload16(const void* g, void* l) {
  __builtin_amdgcn_global_load_lds(
      (__attribute__((address_space(1))) void*)g,
      (__attribute__((address_space(3))) void*)l, 16, 0, 0);
}

// hi/lo bf16 split: x ~= hi + lo, residual ~2^-17 * |x|
__device__ __forceinline__ void split_bf16(float x, unsigned short& hi, unsigned short& lo) {
  __bf16 h = (__bf16)x;
  float r = x - (float)h;
  __bf16 l = (__bf16)r;
  hi = __builtin_bit_cast(unsigned short, h);
  lo = __builtin_bit_cast(unsigned short, l);
}

__device__ __forceinline__ f32x4 mfma16(bf16x8 a, bf16x8 b, f32x4 c) {
  return __builtin_amdgcn_mfma_f32_16x16x32_bf16(a, b, c, 0, 0, 0);
}

__device__ __forceinline__ bf16x8 ldfrag(const void* p) {
  return __builtin_bit_cast(bf16x8, *(const us8*)p);
}

// ---- prep: W1 (1024x512 f32) -> fused swizzled W1F: [n][kt][8 slots of 16B] ----------
// logical slot ls<4: hi bf16 of k = kt*32 + ls*8 .. +8 ; ls>=4: lo of (ls-4) chunk.
// stored at phys slot p = ls ^ (n&7)  (pre-swizzle so gload_lds can be linear).
__global__ __launch_bounds__(256) void k_prep_w1f(const float* __restrict__ W1,
                                                  unsigned short* __restrict__ w1f) {
  const int n = blockIdx.x;   // 0..511
  const int t = threadIdx.x;  // 0..255
  const int kt = t >> 3, ls = t & 7;
  const int p = ls ^ (n & 7);
  const int k0 = kt * 32 + (ls & 3) * 8;
  unsigned short v[8];
#pragma unroll
  for (int e = 0; e < 8; e++) {
    const float x = W1[(size_t)(k0 + e) * HID + n];
    unsigned short h, q;
    split_bf16(x, h, q);
    v[e] = (ls < 4) ? h : q;
  }
  unsigned short* dst = w1f + ((size_t)n * 32 + kt) * 64 + p * 8;
  *(ushort4*)(dst) = make_ushort4(v[0], v[1], v[2], v[3]);
  *(ushort4*)(dst + 4) = make_ushort4(v[4], v[5], v[6], v[7]);
}

// ---------------- prep: W2 (512x92 f32) -> W2T hi/lo bf16 [128][512], rows>=92 zero ----
__global__ __launch_bounds__(256) void k_prep_w2t(const float* __restrict__ W2,
                                                  unsigned short* __restrict__ hi,
                                                  unsigned short* __restrict__ lo) {
  const int idx = blockIdx.x * 256 + threadIdx.x;  // 65536 = 128*512
  const int n = idx >> 9, k = idx & 511;
  const float v = (n < 92) ? W2[(size_t)k * 92 + n] : 0.0f;
  unsigned short h, l;
  split_bf16(v, h, l);
  hi[idx] = h;
  lo[idx] = l;
}

// ---------------- GEMM1: h = silu(z @ W1 + b1) -----------------------------------------
// SINGLE-WAVE blocks: BM=64, BN=64, BK=32; one 64-lane wave per block, wave-tile 64x64,
// 48 MFMA per K-tile (3 terms HH/LH/HL). NO barriers. A direct global->reg + in-reg
// hi/lo split; B via gload_lds into 2x8KB LDS dbuf. Per-wave vmcnt ledger:
// invariant entering iter t = [B(t) 8, A(t) 8]; vmcnt(8) retires B(t); compiler
// handles A-reg waits. 16KB LDS -> 10 blocks/CU: stalls decorrelate across blocks.
__global__ __launch_bounds__(64, 3) void k_gemm1(
    const float* __restrict__ z, const unsigned short* __restrict__ w1f,
    const float* __restrict__ b1,
    unsigned short* __restrict__ hh, unsigned short* __restrict__ hl) {
  __shared__ __attribute__((aligned(16))) char lb[32768];  // 2 x 16KB... (2 x 8KB used x2 safety)

  const int bid = blockIdx.x;
  const int swz = (bid & 7) * 512 + (bid >> 3);  // bijective XCD swizzle (4096 blocks)
  const int mb = swz >> 3, nbk = swz & 7;        // 8 consecutive swz share mb -> z L2 reuse
  const int m0 = mb * 64, n0g = nbk * 64;

  const int l = threadIdx.x;  // 0..63
  const int l15 = l & 15, lg = l >> 4;
  const int xr = l15 & 7;

  // B frag read byte bases (row-local n, 128B/row, phys slot = logical ^ (row&7))
  const int bhB = l15 * 128 + ((lg ^ xr) << 4);
  const int blB = l15 * 128 + ((((4 | lg) ^ xr)) << 4);

  // A direct loads: lane covers z[m0 + mf*16 + l15][kt*32 + lg*8 .. +8]
  const float* zb = z + (size_t)(m0 + l15) * LATENT + lg * 8;

  // B staging: per-lane global src (pre-swizzled layout; linear LDS dest).
  // lane l, step j: n-row = n0g + (l>>3) + 8*j, phys slot (l&7).
  const unsigned short* bsrc =
      w1f + ((size_t)(n0g + (l >> 3)) * 32) * 64 + (l & 7) * 8;

  f32x4 acc[4][4] = {};
  float4 arl[4], arh[4];
  bf16x8 ah[4], alo[4];

#define LOAD_A(kt1)                                                           \
  {                                                                           \
    _Pragma("unroll") for (int mf = 0; mf < 4; mf++) {                        \
      const float* p_ = zb + (size_t)(16 * mf) * LATENT + (kt1) * 32;         \
      arl[mf] = *(const float4*)(p_);                                         \
      arh[mf] = *(const float4*)(p_ + 4);                                     \
    }                                                                         \
  }

#define SPLIT_A                                                               \
  {                                                                           \
    _Pragma("unroll") for (int mf = 0; mf < 4; mf++) {                        \
      _Pragma("unroll") for (int e = 0; e < 4; e++) {                         \
        float f0 = arl[mf][e], f1 = arh[mf][e];                               \
        __bf16 h0 = (__bf16)f0, h1 = (__bf16)f1;                              \
        ah[mf][e] = h0;     alo[mf][e] = (__bf16)(f0 - (float)h0);            \
        ah[mf][4 + e] = h1; alo[mf][4 + e] = (__bf16)(f1 - (float)h1);        \
      }                                                                       \
    }                                                                         \
  }

#define GLOAD_B(bufo, kt1)                                                    \
  {                                                                           \
    _Pragma("unroll") for (int j_ = 0; j_ < 8; j_++)                          \
        gload16(bsrc + (size_t)j_ * 16384 + (kt1) * 64,                       \
                lb + (bufo) + j_ * 1024);                                     \
  }

#define COMPUTE(bufo)                                                         \
  {                                                                           \
    __builtin_amdgcn_s_setprio(1);                                            \
    _Pragma("unroll") for (int nf = 0; nf < 4; nf++) {                        \
      bf16x8 bh = ldfrag(lb + (bufo) + bhB + nf * 2048);                      \
      _Pragma("unroll") for (int mf = 0; mf < 4; mf++)                        \
          acc[mf][nf] = mfma16(ah[mf], bh, acc[mf][nf]);                      \
      _Pragma("unroll") for (int mf = 0; mf < 4; mf++)                        \
          acc[mf][nf] = mfma16(alo[mf], bh, acc[mf][nf]);                     \
    }                                                                         \
    _Pragma("unroll") for (int nf = 0; nf < 4; nf++) {                        \
      bf16x8 bl = ldfrag(lb + (bufo) + blB + nf * 2048);                      \
      _Pragma("unroll") for (int mf = 0; mf < 4; mf++)                        \
          acc[mf][nf] = mfma16(ah[mf], bl, acc[mf][nf]);                      \
    }                                                                         \
    __builtin_amdgcn_s_setprio(0);                                            \
  }

#define FENCE asm volatile("" ::: "memory")

  // ---- prologue: B(0) then A(0): ledger [B0 8, A0 8] ----
  GLOAD_B(0, 0);
  FENCE;
  LOAD_A(0);

  for (int t = 0; t < 32; ++t) {
    const int cb = (t & 1) << 13;   // 8192
    const int nx = cb ^ 8192;

    asm volatile("s_waitcnt vmcnt(8)" ::: "memory");  // B(t) landed in LDS
    if (t < 31) {
      GLOAD_B(nx, t + 1);           // +8 gloads (newest); write nx: its iter t-1
      FENCE;                        //   ds_reads already consumed by MFMAs
    }
    SPLIT_A;                        // compiler inserts vm waits for arl/arh
    if (t < 31) LOAD_A(t + 1);      // +8 reg loads -> invariant restored
    COMPUTE(cb);
  }

  // ---- epilogue: bias + silu + hi/lo split store ----
  float b1v[4];
#pragma unroll
  for (int nf = 0; nf < 4; nf++) b1v[nf] = b1[n0g + nf * 16 + l15];

#pragma unroll
  for (int mf = 0; mf < 4; mf++)
#pragma unroll
    for (int nf = 0; nf < 4; nf++)
#pragma unroll
      for (int r = 0; r < 4; r++) {
        const int gm = m0 + mf * 16 + (lg << 2) + r;
        const int gn = n0g + nf * 16 + l15;
        const float x = acc[mf][nf][r] + b1v[nf];
        const float hval = x / (1.0f + expf(-x));  // silu
        unsigned short hi_, lo_;
        split_bf16(hval, hi_, lo_);
        const size_t o = (size_t)gm * HID + gn;
        hh[o] = hi_;
        hl[o] = lo_;
      }
}

// ---------------- GEMM2 + normalize/softplus/FK epilogue ------------------------------
__global__ __launch_bounds__(256, 2) void k_gemm2(
    const unsigned short* __restrict__ hh, const unsigned short* __restrict__ hl,
    const unsigned short* __restrict__ w2h, const unsigned short* __restrict__ w2l,
    const float* __restrict__ b2, float* __restrict__ out) {
  __shared__ unsigned short Ah[2][2048], Al[2][2048];  // [64][32]
  __shared__ unsigned short Bh[2][4096], Bl[2][4096];  // [128][32]
  __shared__ float raw[64][97];                        // +1 pad: no stride-96 conflicts

  const int tid = threadIdx.x;
  const int m0 = blockIdx.x * 64;
  const int w = tid >> 6, lane = tid & 63;
  const int wr = w >> 1, wc = w & 1;
  const int l15 = lane & 15, lg = lane >> 4;
  const int arow = tid >> 2, ac8 = (tid & 3) << 3;

  const unsigned short* hhb = hh + (size_t)(m0 + arow) * HID + ac8;
  const unsigned short* hlb = hl + (size_t)(m0 + arow) * HID + ac8;
  const unsigned short* w2hb = w2h + (size_t)arow * HID + ac8;
  const unsigned short* w2lb = w2l + (size_t)arow * HID + ac8;

  f32x4 acc[2][3] = {};

#define G2_STAGE(kt, bf) { \
    gload16(hhb + (kt) * 32, &Ah[bf][(w << 9)]); \
    gload16(hlb + (kt) * 32, &Al[bf][(w << 9)]); \
    gload16(w2hb + (kt) * 32,            &Bh[bf][(w << 9)]); \
    gload16(w2hb + (kt) * 32 + 64 * HID, &Bh[bf][2048 + (w << 9)]); \
    gload16(w2lb + (kt) * 32,            &Bl[bf][(w << 9)]); \
    gload16(w2lb + (kt) * 32 + 64 * HID, &Bl[bf][2048 + (w << 9)]); }

#define G2_COMPUTE(bf) { \
    bf16x8 ah2[2], al2[2], bh2[3], bl2[3]; \
    _Pragma("unroll") \
    for (int mf = 0; mf < 2; mf++) { \
      const int o_ = ((wr * 32 + mf * 16 + l15) << 5) + (lg << 3); \
      ah2[mf] = ldfrag(&Ah[bf][o_]); \
      al2[mf] = ldfrag(&Al[bf][o_]); \
    } \
    _Pragma("unroll") \
    for (int nf = 0; nf < 3; nf++) { \
      const int o_ = ((wc * 48 + nf * 16 + l15) << 5) + (lg << 3); \
      bh2[nf] = ldfrag(&Bh[bf][o_]); \
      bl2[nf] = ldfrag(&Bl[bf][o_]); \
    } \
    _Pragma("unroll") \
    for (int mf = 0; mf < 2; mf++) { \
      _Pragma("unroll") \
      for (int nf = 0; nf < 3; nf++) { \
        acc[mf][nf] = mfma16(ah2[mf], bh2[nf], acc[mf][nf]); \
        acc[mf][nf] = mfma16(al2[mf], bh2[nf], acc[mf][nf]); \
        acc[mf][nf] = mfma16(ah2[mf], bl2[nf], acc[mf][nf]); \
      } } }

  G2_STAGE(0, 0);
  __syncthreads();
#pragma unroll 2
  for (int kt = 0; kt < 16; kt++) {
    const int cur = kt & 1, nx = cur ^ 1;
    if (kt < 15) G2_STAGE(kt + 1, nx);
    G2_COMPUTE(cur);
    __syncthreads();
  }

  // acc -> raw LDS (raw = h @ W2, no bias yet; cols 92..95 are zero via W2T pad)
#pragma unroll
  for (int mf = 0; mf < 2; mf++) {
#pragma unroll
    for (int nf = 0; nf < 3; nf++) {
#pragma unroll
      for (int r = 0; r < 4; r++) {
        const int ml = wr * 32 + mf * 16 + (lg << 2) + r;
        const int nl = wc * 48 + nf * 16 + l15;
        raw[ml][nl] = acc[mf][nf][r];
      }
    }
  }
  __syncthreads();

  const size_t OFFB = (size_t)BROWS * 72;   // offsets section
  const size_t LENB = (size_t)BROWS * 144;  // length section

  // phase 1: per (row, joint) -> direction*length, write offsets+length, off in-place
  for (int task = tid; task < 64 * 24; task += 256) {
    const int row = task / 24;
    const int j = task - row * 24;
    const int gm = m0 + row;
    float* orow = out + OFFB + (size_t)gm * 72;
    if (j == 0) {
      orow[0] = 0.0f; orow[1] = 0.0f; orow[2] = 0.0f;
    } else {
      const int c0 = (j - 1) * 4;
      const float vx = raw[row][c0 + 0] + b2[c0 + 0];
      const float vy = raw[row][c0 + 1] + b2[c0 + 1];
      const float vz = raw[row][c0 + 2] + b2[c0 + 2];
      const float wvv = raw[row][c0 + 3] + b2[c0 + 3];
      const float nrm = sqrtf(vx * vx + vy * vy + vz * vz);
      const float inv = 1.0f / fmaxf(nrm, 1e-12f);
      const float len = fmaxf(wvv, 0.0f) + log1pf(expf(-fabsf(wvv)));  // softplus
      const float sc = inv * len;
      const float ox = vx * sc, oy = vy * sc, oz = vz * sc;
      orow[j * 3 + 0] = ox; orow[j * 3 + 1] = oy; orow[j * 3 + 2] = oz;
      out[LENB + (size_t)gm * 23 + (j - 1)] = len;
      raw[row][c0 + 0] = ox; raw[row][c0 + 1] = oy; raw[row][c0 + 2] = oz;
    }
  }
  __syncthreads();

  // phase 2: forward kinematics, one thread per row, fully static unroll
  if (tid < 64) {
    constexpr int PAR[24] = {-1, 0, 0, 0, 1, 2, 3, 4, 5, 6, 7, 8,
                             9, 9, 9, 12, 13, 14, 16, 17, 18, 19, 20, 21};
    const int gm = m0 + tid;
    float e[72];
    e[0] = 0.0f; e[1] = 0.0f; e[2] = 0.0f;
#pragma unroll
    for (int j = 1; j < 24; j++) {
      const int p = PAR[j];
      const int c0 = (j - 1) * 4;
      e[3 * j + 0] = e[3 * p + 0] + raw[tid][c0 + 0];
      e[3 * j + 1] = e[3 * p + 1] + raw[tid][c0 + 1];
      e[3 * j + 2] = e[3 * p + 2] + raw[tid][c0 + 2];
    }
    float4* jo = (float4*)(out + (size_t)gm * 72);
#pragma unroll
    for (int q = 0; q < 18; q++)
      jo[q] = make_float4(e[4 * q + 0], e[4 * q + 1], e[4 * q + 2], e[4 * q + 3]);
  }
}

extern "C" void kernel_launch(void* const* d_in, const int* in_sizes, int n_in,
                              void* d_out, int out_size, void* d_ws, size_t ws_size,
                              hipStream_t stream) {
  const float* z = (const float*)d_in[0];
  const float* W1 = (const float*)d_in[1];
  const float* b1 = (const float*)d_in[2];
  const float* W2 = (const float*)d_in[3];
  const float* b2 = (const float*)d_in[4];
  float* out = (float*)d_out;

  char* ws = (char*)d_ws;
  unsigned short* w1f = (unsigned short*)(ws);                                  // 2 MB
  unsigned short* w2h = (unsigned short*)(ws + (2 << 20));                      // 128 KB
  unsigned short* w2l = (unsigned short*)(ws + (2 << 20) + 131072);             // 128 KB
  unsigned short* hh = (unsigned short*)(ws + ((size_t)4 << 20));               // 32 MB
  unsigned short* hl = (unsigned short*)(ws + ((size_t)4 << 20) + ((size_t)32 << 20));  // 32 MB

  hipLaunchKernelGGL(k_prep_w1f, dim3(512), dim3(256), 0, stream, W1, w1f);
  hipLaunchKernelGGL(k_prep_w2t, dim3(256), dim3(256), 0, stream, W2, w2h, w2l);
  hipLaunchKernelGGL(k_gemm1, dim3(4096), dim3(64), 0, stream, z, w1f, b1, hh, hl);
  hipLaunchKernelGGL(k_gemm2, dim3(512), dim3(256), 0, stream, hh, hl, w2h, w2l, b2, out);
}

// Round 7
// 157.143 us; speedup vs baseline: 1.5544x; 1.5544x over previous
//
#include <hip/hip_runtime.h>
#include <hip/hip_bf16.h>
#include <stdint.h>

#define BROWS 32768
#define LATENT 1024
#define HID 512

typedef float f32x4 __attribute__((ext_vector_type(4)));
typedef __bf16 bf16x8 __attribute__((ext_vector_type(8)));
typedef unsigned short us8 __attribute__((ext_vector_type(8)));

__device__ __forceinline__ void gload16(const void* g, void* l) {
  __builtin_amdgcn_global_load_lds(
      (__attribute__((address_space(1))) void*)g,
      (__attribute__((address_space(3))) void*)l, 16, 0, 0);
}

// hi/lo bf16 split: x ~= hi + lo, residual ~2^-17 * |x|
__device__ __forceinline__ void split_bf16(float x, unsigned short& hi, unsigned short& lo) {
  __bf16 h = (__bf16)x;
  float r = x - (float)h;
  __bf16 l = (__bf16)r;
  hi = __builtin_bit_cast(unsigned short, h);
  lo = __builtin_bit_cast(unsigned short, l);
}

__device__ __forceinline__ f32x4 mfma16(bf16x8 a, bf16x8 b, f32x4 c) {
  return __builtin_amdgcn_mfma_f32_16x16x32_bf16(a, b, c, 0, 0, 0);
}

__device__ __forceinline__ bf16x8 ldfrag(const void* p) {
  return __builtin_bit_cast(bf16x8, *(const us8*)p);
}

// ---- prep: W1 (1024x512 f32) -> fused swizzled W1F: [n][kt][8 slots of 16B] ----------
// logical slot ls<4: hi bf16 of k = kt*32 + ls*8 .. +8 ; ls>=4: lo of (ls-4) chunk.
// stored at phys slot p = ls ^ (n&7)  (pre-swizzle so gload_lds can be linear).
__global__ __launch_bounds__(256) void k_prep_w1f(const float* __restrict__ W1,
                                                  unsigned short* __restrict__ w1f) {
  const int n = blockIdx.x;   // 0..511
  const int t = threadIdx.x;  // 0..255
  const int kt = t >> 3, ls = t & 7;
  const int p = ls ^ (n & 7);
  const int k0 = kt * 32 + (ls & 3) * 8;
  unsigned short v[8];
#pragma unroll
  for (int e = 0; e < 8; e++) {
    const float x = W1[(size_t)(k0 + e) * HID + n];
    unsigned short h, q;
    split_bf16(x, h, q);
    v[e] = (ls < 4) ? h : q;
  }
  unsigned short* dst = w1f + ((size_t)n * 32 + kt) * 64 + p * 8;
  *(ushort4*)(dst) = make_ushort4(v[0], v[1], v[2], v[3]);
  *(ushort4*)(dst + 4) = make_ushort4(v[4], v[5], v[6], v[7]);
}

// ---------------- prep: W2 (512x92 f32) -> W2T hi/lo bf16 [128][512], rows>=92 zero ----
__global__ __launch_bounds__(256) void k_prep_w2t(const float* __restrict__ W2,
                                                  unsigned short* __restrict__ hi,
                                                  unsigned short* __restrict__ lo) {
  const int idx = blockIdx.x * 256 + threadIdx.x;  // 65536 = 128*512
  const int n = idx >> 9, k = idx & 511;
  const float v = (n < 92) ? W2[(size_t)k * 92 + n] : 0.0f;
  unsigned short h, l;
  split_bf16(v, h, l);
  hi[idx] = h;
  lo[idx] = l;
}

// ---------------- GEMM1: h = silu(z @ W1 + b1) -----------------------------------------
// BM=128, BN=256, BK=32, 8 waves (2m x 4n), wave-tile 64x64. z staged to LDS as f32
// (swizzled via pre-swizzled per-lane global source); hi/lo split at READ time.
// 3 phases/K-step (HH/LH/HL, 16 MFMA each) with reads hoisted ONE PHASE AHEAD:
//   P1: read Bl(t) + issue stage(t+1); bar; MFMA HH (A/Bh pre-read at P3(t-1))
//   P2: split-lo; MFMA LH (pure reg)
//   P3: vmcnt(0); bar; MFMA HL; pre-read A(t+1)+Bh(t+1); bar
// LDS 2 bufs x (A 16KB f32 + B 32KB bf16) = 96KB, 1 block/CU, 2 waves/SIMD.
__global__ __launch_bounds__(512, 2) void k_gemm1(
    const float* __restrict__ z, const unsigned short* __restrict__ w1f,
    const float* __restrict__ b1,
    unsigned short* __restrict__ hh, unsigned short* __restrict__ hl) {
  extern __shared__ __align__(16) char lb[];

  const int tid = threadIdx.x;
  const int bid = blockIdx.x;
  const int swz = (bid & 7) * 64 + (bid >> 3);  // bijective XCD swizzle (512 blocks)
  const int mb = swz >> 1, nbk = swz & 1;       // n-pair adjacent on same XCD
  const int m0 = mb * 128, n0g = nbk * 256;

  const int wv = tid >> 6, l = tid & 63;
  const int wr = wv >> 2, wc = wv & 3;  // wave grid 2m x 4n
  const int l15 = l & 15, lg = l >> 4;
  const int x7 = l15 & 7;

  // frag read bases (A region @0 f32 [128 rows][128B]; B region @16384 [256 rows][128B])
  const int rowAB = (wr * 64 + l15) * 128;              // A row base bytes
  const int sA0 = (((2 * lg) ^ x7)) << 4;
  const int sA1 = (((2 * lg + 1) ^ x7)) << 4;
  const int rowBB = 16384 + (wc * 64 + l15) * 128;      // B row base bytes
  const int sBH = ((lg ^ x7)) << 4;
  const int sBL = ((((4 | lg)) ^ x7)) << 4;

  // staging sources (pre-swizzled per-lane global addresses; linear LDS dest)
  const int lr = l >> 3, lc = l & 7;
  const char* zA0 = (const char*)z +
      ((size_t)(m0 + wv * 16 + lr)) * 4096 + ((lc ^ (lr & 7)) << 4);
  const char* zB0 = (const char*)w1f +
      ((size_t)(n0g + wv * 32 + lr)) * 4096 + (lc << 4);

  f32x4 acc[4][4] = {};
  f32x4 af[4][2];
  bf16x8 ah[4], al[4], bhf[4], blf[4];

#define STAGE(nbase, kt1)                                                     \
  {                                                                           \
    _Pragma("unroll") for (int j_ = 0; j_ < 2; j_++)                          \
        gload16(zA0 + (size_t)j_ * 32768 + (kt1) * 128,                       \
                lb + (nbase) + (wv * 2 + j_) * 1024);                         \
    _Pragma("unroll") for (int j_ = 0; j_ < 4; j_++)                          \
        gload16(zB0 + (size_t)j_ * 32768 + (kt1) * 128,                       \
                lb + (nbase) + 16384 + (wv * 4 + j_) * 1024);                 \
  }

#define LD_A(cb)                                                              \
  {                                                                           \
    _Pragma("unroll") for (int mf = 0; mf < 4; mf++) {                        \
      af[mf][0] = *(const f32x4*)(lb + (cb) + rowAB + mf * 2048 + sA0);       \
      af[mf][1] = *(const f32x4*)(lb + (cb) + rowAB + mf * 2048 + sA1);       \
    }                                                                         \
  }

#define LD_BH(cb)                                                             \
  {                                                                           \
    _Pragma("unroll") for (int nf = 0; nf < 4; nf++)                          \
        bhf[nf] = ldfrag(lb + (cb) + rowBB + nf * 2048 + sBH);                \
  }

#define LD_BL(cb)                                                             \
  {                                                                           \
    _Pragma("unroll") for (int nf = 0; nf < 4; nf++)                          \
        blf[nf] = ldfrag(lb + (cb) + rowBB + nf * 2048 + sBL);                \
  }

#define SPLIT_HI                                                              \
  {                                                                           \
    _Pragma("unroll") for (int mf = 0; mf < 4; mf++)                          \
        _Pragma("unroll") for (int e = 0; e < 4; e++) {                       \
      ah[mf][e] = (__bf16)af[mf][0][e];                                       \
      ah[mf][4 + e] = (__bf16)af[mf][1][e];                                   \
    }                                                                         \
  }

#define SPLIT_LO                                                              \
  {                                                                           \
    _Pragma("unroll") for (int mf = 0; mf < 4; mf++)                          \
        _Pragma("unroll") for (int e = 0; e < 4; e++) {                       \
      al[mf][e] = (__bf16)(af[mf][0][e] - (float)ah[mf][e]);                  \
      al[mf][4 + e] = (__bf16)(af[mf][1][e] - (float)ah[mf][4 + e]);          \
    }                                                                         \
  }

#define MCL(AF, BF)                                                           \
  {                                                                           \
    __builtin_amdgcn_s_setprio(1);                                            \
    _Pragma("unroll") for (int mf = 0; mf < 4; mf++)                          \
        _Pragma("unroll") for (int nf = 0; nf < 4; nf++)                      \
            acc[mf][nf] = mfma16(AF[mf], BF[nf], acc[mf][nf]);                \
    __builtin_amdgcn_s_setprio(0);                                            \
  }

#define SBAR { asm volatile("" ::: "memory"); __builtin_amdgcn_s_barrier();   \
               asm volatile("" ::: "memory"); }
#define VM0  asm volatile("s_waitcnt vmcnt(0)" ::: "memory")

  // ---- prologue: stage(0); drain; pre-read A(0),Bh(0) ----
  STAGE(0, 0);
  VM0;
  SBAR;
  LD_A(0);
  LD_BH(0);

#pragma unroll 2
  for (int t = 0; t < 32; ++t) {
    const int cb = (t & 1) * 49152;
    const int nb = cb ^ 49152;
    const bool pre = (t < 31);

    // ---- P1: HH ----
    LD_BL(cb);
    if (pre) STAGE(nb, t + 1);
    SBAR;
    SPLIT_HI;
    MCL(ah, bhf);
    SBAR;

    // ---- P2: LH (pure reg) ----
    SPLIT_LO;
    MCL(al, bhf);

    // ---- P3: HL + pre-read next ----
    VM0;            // stage(t+1) landed (per-wave) ...
    SBAR;           // ... and for ALL waves
    MCL(ah, blf);
    if (pre) {
      LD_A(nb);
      LD_BH(nb);
    }
    SBAR;
  }

  // ---- epilogue: bias + silu + hi/lo split store ----
  float b1v[4];
#pragma unroll
  for (int nf = 0; nf < 4; nf++) b1v[nf] = b1[n0g + wc * 64 + nf * 16 + l15];

#pragma unroll
  for (int mf = 0; mf < 4; mf++)
#pragma unroll
    for (int nf = 0; nf < 4; nf++)
#pragma unroll
      for (int r = 0; r < 4; r++) {
        const int gm = m0 + wr * 64 + mf * 16 + (lg << 2) + r;
        const int gn = n0g + wc * 64 + nf * 16 + l15;
        const float x = acc[mf][nf][r] + b1v[nf];
        const float hval = x / (1.0f + expf(-x));  // silu
        unsigned short hi_, lo_;
        split_bf16(hval, hi_, lo_);
        const size_t o = (size_t)gm * HID + gn;
        hh[o] = hi_;
        hl[o] = lo_;
      }
}

// ---------------- GEMM2 + normalize/softplus/FK epilogue ------------------------------
__global__ __launch_bounds__(256, 2) void k_gemm2(
    const unsigned short* __restrict__ hh, const unsigned short* __restrict__ hl,
    const unsigned short* __restrict__ w2h, const unsigned short* __restrict__ w2l,
    const float* __restrict__ b2, float* __restrict__ out) {
  __shared__ unsigned short Ah[2][2048], Al[2][2048];  // [64][32]
  __shared__ unsigned short Bh[2][4096], Bl[2][4096];  // [128][32]
  __shared__ float raw[64][97];                        // +1 pad: no stride-96 conflicts

  const int tid = threadIdx.x;
  const int m0 = blockIdx.x * 64;
  const int w = tid >> 6, lane = tid & 63;
  const int wr = w >> 1, wc = w & 1;
  const int l15 = lane & 15, lg = lane >> 4;
  const int arow = tid >> 2, ac8 = (tid & 3) << 3;

  const unsigned short* hhb = hh + (size_t)(m0 + arow) * HID + ac8;
  const unsigned short* hlb = hl + (size_t)(m0 + arow) * HID + ac8;
  const unsigned short* w2hb = w2h + (size_t)arow * HID + ac8;
  const unsigned short* w2lb = w2l + (size_t)arow * HID + ac8;

  f32x4 acc[2][3] = {};

#define G2_STAGE(kt, bf) { \
    gload16(hhb + (kt) * 32, &Ah[bf][(w << 9)]); \
    gload16(hlb + (kt) * 32, &Al[bf][(w << 9)]); \
    gload16(w2hb + (kt) * 32,            &Bh[bf][(w << 9)]); \
    gload16(w2hb + (kt) * 32 + 64 * HID, &Bh[bf][2048 + (w << 9)]); \
    gload16(w2lb + (kt) * 32,            &Bl[bf][(w << 9)]); \
    gload16(w2lb + (kt) * 32 + 64 * HID, &Bl[bf][2048 + (w << 9)]); }

#define G2_COMPUTE(bf) { \
    bf16x8 ah2[2], al2[2], bh2[3], bl2[3]; \
    _Pragma("unroll") \
    for (int mf = 0; mf < 2; mf++) { \
      const int o_ = ((wr * 32 + mf * 16 + l15) << 5) + (lg << 3); \
      ah2[mf] = ldfrag(&Ah[bf][o_]); \
      al2[mf] = ldfrag(&Al[bf][o_]); \
    } \
    _Pragma("unroll") \
    for (int nf = 0; nf < 3; nf++) { \
      const int o_ = ((wc * 48 + nf * 16 + l15) << 5) + (lg << 3); \
      bh2[nf] = ldfrag(&Bh[bf][o_]); \
      bl2[nf] = ldfrag(&Bl[bf][o_]); \
    } \
    _Pragma("unroll") \
    for (int mf = 0; mf < 2; mf++) { \
      _Pragma("unroll") \
      for (int nf = 0; nf < 3; nf++) { \
        acc[mf][nf] = mfma16(ah2[mf], bh2[nf], acc[mf][nf]); \
        acc[mf][nf] = mfma16(al2[mf], bh2[nf], acc[mf][nf]); \
        acc[mf][nf] = mfma16(ah2[mf], bl2[nf], acc[mf][nf]); \
      } } }

  G2_STAGE(0, 0);
  __syncthreads();
#pragma unroll 2
  for (int kt = 0; kt < 16; kt++) {
    const int cur = kt & 1, nx = cur ^ 1;
    if (kt < 15) G2_STAGE(kt + 1, nx);
    G2_COMPUTE(cur);
    __syncthreads();
  }

  // acc -> raw LDS (raw = h @ W2, no bias yet; cols 92..95 are zero via W2T pad)
#pragma unroll
  for (int mf = 0; mf < 2; mf++) {
#pragma unroll
    for (int nf = 0; nf < 3; nf++) {
#pragma unroll
      for (int r = 0; r < 4; r++) {
        const int ml = wr * 32 + mf * 16 + (lg << 2) + r;
        const int nl = wc * 48 + nf * 16 + l15;
        raw[ml][nl] = acc[mf][nf][r];
      }
    }
  }
  __syncthreads();

  const size_t OFFB = (size_t)BROWS * 72;   // offsets section
  const size_t LENB = (size_t)BROWS * 144;  // length section

  // phase 1: per (row, joint) -> direction*length, write offsets+length, off in-place
  for (int task = tid; task < 64 * 24; task += 256) {
    const int row = task / 24;
    const int j = task - row * 24;
    const int gm = m0 + row;
    float* orow = out + OFFB + (size_t)gm * 72;
    if (j == 0) {
      orow[0] = 0.0f; orow[1] = 0.0f; orow[2] = 0.0f;
    } else {
      const int c0 = (j - 1) * 4;
      const float vx = raw[row][c0 + 0] + b2[c0 + 0];
      const float vy = raw[row][c0 + 1] + b2[c0 + 1];
      const float vz = raw[row][c0 + 2] + b2[c0 + 2];
      const float wvv = raw[row][c0 + 3] + b2[c0 + 3];
      const float nrm = sqrtf(vx * vx + vy * vy + vz * vz);
      const float inv = 1.0f / fmaxf(nrm, 1e-12f);
      const float len = fmaxf(wvv, 0.0f) + log1pf(expf(-fabsf(wvv)));  // softplus
      const float sc = inv * len;
      const float ox = vx * sc, oy = vy * sc, oz = vz * sc;
      orow[j * 3 + 0] = ox; orow[j * 3 + 1] = oy; orow[j * 3 + 2] = oz;
      out[LENB + (size_t)gm * 23 + (j - 1)] = len;
      raw[row][c0 + 0] = ox; raw[row][c0 + 1] = oy; raw[row][c0 + 2] = oz;
    }
  }
  __syncthreads();

  // phase 2: forward kinematics, one thread per row, fully static unroll
  if (tid < 64) {
    constexpr int PAR[24] = {-1, 0, 0, 0, 1, 2, 3, 4, 5, 6, 7, 8,
                             9, 9, 9, 12, 13, 14, 16, 17, 18, 19, 20, 21};
    const int gm = m0 + tid;
    float e[72];
    e[0] = 0.0f; e[1] = 0.0f; e[2] = 0.0f;
#pragma unroll
    for (int j = 1; j < 24; j++) {
      const int p = PAR[j];
      const int c0 = (j - 1) * 4;
      e[3 * j + 0] = e[3 * p + 0] + raw[tid][c0 + 0];
      e[3 * j + 1] = e[3 * p + 1] + raw[tid][c0 + 1];
      e[3 * j + 2] = e[3 * p + 2] + raw[tid][c0 + 2];
    }
    float4* jo = (float4*)(out + (size_t)gm * 72);
#pragma unroll
    for (int q = 0; q < 18; q++)
      jo[q] = make_float4(e[4 * q + 0], e[4 * q + 1], e[4 * q + 2], e[4 * q + 3]);
  }
}

extern "C" void kernel_launch(void* const* d_in, const int* in_sizes, int n_in,
                              void* d_out, int out_size, void* d_ws, size_t ws_size,
                              hipStream_t stream) {
  const float* z = (const float*)d_in[0];
  const float* W1 = (const float*)d_in[1];
  const float* b1 = (const float*)d_in[2];
  const float* W2 = (const float*)d_in[3];
  const float* b2 = (const float*)d_in[4];
  float* out = (float*)d_out;

  char* ws = (char*)d_ws;
  unsigned short* w1f = (unsigned short*)(ws);                                  // 2 MB
  unsigned short* w2h = (unsigned short*)(ws + (2 << 20));                      // 128 KB
  unsigned short* w2l = (unsigned short*)(ws + (2 << 20) + 131072);             // 128 KB
  unsigned short* hh = (unsigned short*)(ws + ((size_t)4 << 20));               // 32 MB
  unsigned short* hl = (unsigned short*)(ws + ((size_t)4 << 20) + ((size_t)32 << 20));  // 32 MB

  hipFuncSetAttribute((const void*)k_gemm1,
                      hipFuncAttributeMaxDynamicSharedMemorySize, 98304);

  hipLaunchKernelGGL(k_prep_w1f, dim3(512), dim3(256), 0, stream, W1, w1f);
  hipLaunchKernelGGL(k_prep_w2t, dim3(256), dim3(256), 0, stream, W2, w2h, w2l);
  hipLaunchKernelGGL(k_gemm1, dim3(512), dim3(512), 98304, stream, z, w1f, b1, hh, hl);
  hipLaunchKernelGGL(k_gemm2, dim3(512), dim3(256), 0, stream, hh, hl, w2h, w2l, b2, out);
}

// Round 8
// 153.742 us; speedup vs baseline: 1.5888x; 1.0221x over previous
//
#include <hip/hip_runtime.h>
#include <hip/hip_bf16.h>
#include <stdint.h>

#define BROWS 32768
#define LATENT 1024
#define HID 512

typedef float f32x4 __attribute__((ext_vector_type(4)));
typedef __bf16 bf16x8 __attribute__((ext_vector_type(8)));
typedef unsigned short us8 __attribute__((ext_vector_type(8)));

__device__ __forceinline__ void gload16(const void* g, void* l) {
  __builtin_amdgcn_global_load_lds(
      (__attribute__((address_space(1))) void*)g,
      (__attribute__((address_space(3))) void*)l, 16, 0, 0);
}

// hi/lo bf16 split: x ~= hi + lo, residual ~2^-17 * |x|
__device__ __forceinline__ void split_bf16(float x, unsigned short& hi, unsigned short& lo) {
  __bf16 h = (__bf16)x;
  float r = x - (float)h;
  __bf16 l = (__bf16)r;
  hi = __builtin_bit_cast(unsigned short, h);
  lo = __builtin_bit_cast(unsigned short, l);
}

__device__ __forceinline__ f32x4 mfma16(bf16x8 a, bf16x8 b, f32x4 c) {
  return __builtin_amdgcn_mfma_f32_16x16x32_bf16(a, b, c, 0, 0, 0);
}

__device__ __forceinline__ bf16x8 ldfrag(const void* p) {
  return __builtin_bit_cast(bf16x8, *(const us8*)p);
}

// ---- prep: W1 (1024x512 f32) -> fused swizzled W1F: [n][kt][8 slots of 16B] ----------
// logical slot ls<4: hi bf16 of k = kt*32 + ls*8 .. +8 ; ls>=4: lo of (ls-4) chunk.
// stored at phys slot p = ls ^ (n&7)  (pre-swizzle so gload_lds can be linear).
__global__ __launch_bounds__(256) void k_prep_w1f(const float* __restrict__ W1,
                                                  unsigned short* __restrict__ w1f) {
  const int n = blockIdx.x;   // 0..511
  const int t = threadIdx.x;  // 0..255
  const int kt = t >> 3, ls = t & 7;
  const int p = ls ^ (n & 7);
  const int k0 = kt * 32 + (ls & 3) * 8;
  unsigned short v[8];
#pragma unroll
  for (int e = 0; e < 8; e++) {
    const float x = W1[(size_t)(k0 + e) * HID + n];
    unsigned short h, q;
    split_bf16(x, h, q);
    v[e] = (ls < 4) ? h : q;
  }
  unsigned short* dst = w1f + ((size_t)n * 32 + kt) * 64 + p * 8;
  *(ushort4*)(dst) = make_ushort4(v[0], v[1], v[2], v[3]);
  *(ushort4*)(dst + 4) = make_ushort4(v[4], v[5], v[6], v[7]);
}

// ---------------- prep: W2 (512x92 f32) -> W2T hi/lo bf16 [128][512], rows>=92 zero ----
__global__ __launch_bounds__(256) void k_prep_w2t(const float* __restrict__ W2,
                                                  unsigned short* __restrict__ hi,
                                                  unsigned short* __restrict__ lo) {
  const int idx = blockIdx.x * 256 + threadIdx.x;  // 65536 = 128*512
  const int n = idx >> 9, k = idx & 511;
  const float v = (n < 92) ? W2[(size_t)k * 92 + n] : 0.0f;
  unsigned short h, l;
  split_bf16(v, h, l);
  hi[idx] = h;
  lo[idx] = l;
}

// ---------------- GEMM1: h = silu(z @ W1 + b1) -----------------------------------------
// BM=128, BN=128, BK=32, 4 waves (2m x 2n), wave-tile 64x64, 48 MFMA/K-tile in
// 3 phases of 16 (HH/LH/HL). m201 phase discipline: per phase
//   {ds_reads for THIS cluster; (staging issue); BAR; lgkm0; prio1; 16 MFMA; prio0; BAR}
// A staged global->reg->split->ds_write (pre-split bf16, once per element); B staged
// via gload_lds from pre-swizzled w1f. LDS 2 x 32KB dbuf -> 2 blocks/CU.
// Counted vmcnt(4) is a perf hint; correctness carried by compiler reg-deps +
// vmcnt(0)/lgkm0 before the tile-final barrier.
__global__ __launch_bounds__(256, 2) void k_gemm1(
    const float* __restrict__ z, const unsigned short* __restrict__ w1f,
    const float* __restrict__ b1,
    unsigned short* __restrict__ hh, unsigned short* __restrict__ hl) {
  extern __shared__ __align__(16) char lb[];

  const int tid = threadIdx.x;
  const int bid = blockIdx.x;
  const int swz = (bid & 7) * 128 + (bid >> 3);  // bijective XCD swizzle (1024 blocks)
  const int mb = swz >> 2, nbk = swz & 3;
  const int m0 = mb * 128, n0g = nbk * 128;

  const int wv = tid >> 6, l = tid & 63;
  const int wr = wv >> 1, wc = wv & 1;  // wave grid 2m x 2n
  const int l15 = l & 15, lg = l >> 4;
  const int x7 = l15 & 7;

  // frag read byte bases within a buffer.
  // A region @0: [128 rows][128B]; B region @16384: [128 rows][128B].
  // 128B row = 8 slots of 16B; phys slot = logical ^ (row&7). hi slots 0-3, lo 4-7.
  const int ahB = (wr * 64 + l15) * 128 + ((lg ^ x7) << 4);
  const int alB = (wr * 64 + l15) * 128 + ((((4 | lg) ^ x7)) << 4);
  const int bhB = 16384 + (wc * 64 + l15) * 128 + ((lg ^ x7) << 4);
  const int blB = 16384 + (wc * 64 + l15) * 128 + ((((4 | lg) ^ x7)) << 4);

  // A staging: thread covers row arow = tid>>1, floats k0a..k0a+16 (4 dwordx4)
  const int arow = tid >> 1;
  const int k0a = (tid & 1) * 16;
  const float* zsrc = z + (size_t)(m0 + arow) * LATENT + k0a;
  // per-chunk q (k = k0a + 4q): hi dst slot (k>>3)^(arow&7), 8B-half (k>>2)&1
  int adst_hi[4], adst_lo[4];
#pragma unroll
  for (int q = 0; q < 4; q++) {
    const int k = k0a + 4 * q;
    const int sl = k >> 3, hf = ((k >> 2) & 1) * 8;
    adst_hi[q] = arow * 128 + ((sl ^ (arow & 7)) << 4) + hf;
    adst_lo[q] = arow * 128 + ((((4 | sl)) ^ (arow & 7)) << 4) + hf;
  }

  // B staging: thread j=0..3 -> n_local = (tid>>3) + 32j, phys slot tid&7 (linear dst)
  const unsigned short* bsrc =
      w1f + ((size_t)(n0g + (tid >> 3)) * 32) * 64 + (tid & 7) * 8;
  const int bdst = 16384 + (tid >> 3) * 128 + (tid & 7) * 16;

  f32x4 acc[4][4] = {};
  f32x4 ar[4];
  bf16x8 ah[4], al[4], bh[4], bl[4];

#define LOAD_A(kt1)                                                           \
  {                                                                           \
    _Pragma("unroll") for (int q = 0; q < 4; q++)                             \
        ar[q] = *(const f32x4*)(zsrc + (kt1) * 32 + 4 * q);                   \
  }

#define GLOAD_B(nbase, kt1)                                                   \
  {                                                                           \
    _Pragma("unroll") for (int j_ = 0; j_ < 4; j_++)                          \
        gload16(bsrc + (size_t)j_ * 65536 + (kt1) * 64,                       \
                lb + (nbase) + bdst + j_ * 4096);                             \
  }

#define SPLIT_WRITE(nbase)                                                    \
  {                                                                           \
    _Pragma("unroll") for (int q = 0; q < 4; q++) {                           \
      unsigned short h0, h1, h2, h3, q0, q1, q2, q3;                          \
      split_bf16(ar[q][0], h0, q0); split_bf16(ar[q][1], h1, q1);             \
      split_bf16(ar[q][2], h2, q2); split_bf16(ar[q][3], h3, q3);             \
      *(ushort4*)(lb + (nbase) + adst_hi[q]) = make_ushort4(h0, h1, h2, h3);  \
      *(ushort4*)(lb + (nbase) + adst_lo[q]) = make_ushort4(q0, q1, q2, q3);  \
    }                                                                         \
  }

#define LD4(dst, cb, base)                                                    \
  {                                                                           \
    _Pragma("unroll") for (int f_ = 0; f_ < 4; f_++)                          \
        dst[f_] = ldfrag(lb + (cb) + (base) + f_ * 2048);                     \
  }

#define MCL(AF, BF)                                                           \
  {                                                                           \
    __builtin_amdgcn_s_setprio(1);                                            \
    _Pragma("unroll") for (int mf = 0; mf < 4; mf++)                          \
        _Pragma("unroll") for (int nf = 0; nf < 4; nf++)                      \
            acc[mf][nf] = mfma16(AF[mf], BF[nf], acc[mf][nf]);                \
    __builtin_amdgcn_s_setprio(0);                                            \
  }

#define FENCE asm volatile("" ::: "memory")
#define SBAR { FENCE; __builtin_amdgcn_s_barrier(); FENCE; }
#define LGKM0 asm volatile("s_waitcnt lgkmcnt(0)" ::: "memory")
#define VM4 asm volatile("s_waitcnt vmcnt(4)" ::: "memory")
#define VM0 asm volatile("s_waitcnt vmcnt(0)" ::: "memory")

  // ---- prologue: fully stage tile 0 into buf 0 ----
  LOAD_A(0);
  FENCE;
  GLOAD_B(0, 0);
  VM4;              // A(0) regs ready (hint; compiler also enforces)
  SPLIT_WRITE(0);
  VM0;              // B(0) resident in LDS
  LGKM0;            // A writes drained
  SBAR;

  for (int t = 0; t < 32; ++t) {
    const int cb = (t & 1) * 32768;
    const int nb = cb ^ 32768;
    const bool pre = (t < 31);

    // ---- P1: HH ----
    LD4(ah, cb, ahB);
    LD4(bh, cb, bhB);
    if (pre) {
      LOAD_A(t + 1);   // issued FIRST in vm ledger
      FENCE;
      GLOAD_B(nb, t + 1);
    }
    SBAR; LGKM0;
    MCL(ah, bh);
    SBAR;

    // ---- P2: LH ----
    LD4(al, cb, alB);
    SBAR; LGKM0;
    MCL(al, bh);
    SBAR;

    // ---- P3: HL ----
    LD4(bl, cb, blB);
    if (pre) {
      VM4;                 // A(t+1) regs landed; B(t+1) may still fly
      SPLIT_WRITE(nb);
      VM0;                 // B(t+1) LDS-resident (issued ~2 phases ago)
    }
    LGKM0;                 // own reads + writes drained before barrier
    SBAR;
    MCL(ah, bl);
    SBAR;
  }

  // ---- epilogue: bias + silu + hi/lo split store ----
  float b1v[4];
#pragma unroll
  for (int nf = 0; nf < 4; nf++) b1v[nf] = b1[n0g + wc * 64 + nf * 16 + l15];

#pragma unroll
  for (int mf = 0; mf < 4; mf++)
#pragma unroll
    for (int nf = 0; nf < 4; nf++)
#pragma unroll
      for (int r = 0; r < 4; r++) {
        const int gm = m0 + wr * 64 + mf * 16 + (lg << 2) + r;
        const int gn = n0g + wc * 64 + nf * 16 + l15;
        const float x = acc[mf][nf][r] + b1v[nf];
        const float hval = x / (1.0f + expf(-x));  // silu
        unsigned short hi_, lo_;
        split_bf16(hval, hi_, lo_);
        const size_t o = (size_t)gm * HID + gn;
        hh[o] = hi_;
        hl[o] = lo_;
      }
}

// ---------------- GEMM2 + normalize/softplus/FK epilogue ------------------------------
__global__ __launch_bounds__(256, 2) void k_gemm2(
    const unsigned short* __restrict__ hh, const unsigned short* __restrict__ hl,
    const unsigned short* __restrict__ w2h, const unsigned short* __restrict__ w2l,
    const float* __restrict__ b2, float* __restrict__ out) {
  __shared__ unsigned short Ah[2][2048], Al[2][2048];  // [64][32]
  __shared__ unsigned short Bh[2][4096], Bl[2][4096];  // [128][32]
  __shared__ float raw[64][97];                        // +1 pad: no stride-96 conflicts

  const int tid = threadIdx.x;
  const int m0 = blockIdx.x * 64;
  const int w = tid >> 6, lane = tid & 63;
  const int wr = w >> 1, wc = w & 1;
  const int l15 = lane & 15, lg = lane >> 4;
  const int arow = tid >> 2, ac8 = (tid & 3) << 3;

  const unsigned short* hhb = hh + (size_t)(m0 + arow) * HID + ac8;
  const unsigned short* hlb = hl + (size_t)(m0 + arow) * HID + ac8;
  const unsigned short* w2hb = w2h + (size_t)arow * HID + ac8;
  const unsigned short* w2lb = w2l + (size_t)arow * HID + ac8;

  f32x4 acc[2][3] = {};

#define G2_STAGE(kt, bf) { \
    gload16(hhb + (kt) * 32, &Ah[bf][(w << 9)]); \
    gload16(hlb + (kt) * 32, &Al[bf][(w << 9)]); \
    gload16(w2hb + (kt) * 32,            &Bh[bf][(w << 9)]); \
    gload16(w2hb + (kt) * 32 + 64 * HID, &Bh[bf][2048 + (w << 9)]); \
    gload16(w2lb + (kt) * 32,            &Bl[bf][(w << 9)]); \
    gload16(w2lb + (kt) * 32 + 64 * HID, &Bl[bf][2048 + (w << 9)]); }

#define G2_COMPUTE(bf) { \
    bf16x8 ah2[2], al2[2], bh2[3], bl2[3]; \
    _Pragma("unroll") \
    for (int mf = 0; mf < 2; mf++) { \
      const int o_ = ((wr * 32 + mf * 16 + l15) << 5) + (lg << 3); \
      ah2[mf] = ldfrag(&Ah[bf][o_]); \
      al2[mf] = ldfrag(&Al[bf][o_]); \
    } \
    _Pragma("unroll") \
    for (int nf = 0; nf < 3; nf++) { \
      const int o_ = ((wc * 48 + nf * 16 + l15) << 5) + (lg << 3); \
      bh2[nf] = ldfrag(&Bh[bf][o_]); \
      bl2[nf] = ldfrag(&Bl[bf][o_]); \
    } \
    _Pragma("unroll") \
    for (int mf = 0; mf < 2; mf++) { \
      _Pragma("unroll") \
      for (int nf = 0; nf < 3; nf++) { \
        acc[mf][nf] = mfma16(ah2[mf], bh2[nf], acc[mf][nf]); \
        acc[mf][nf] = mfma16(al2[mf], bh2[nf], acc[mf][nf]); \
        acc[mf][nf] = mfma16(ah2[mf], bl2[nf], acc[mf][nf]); \
      } } }

  G2_STAGE(0, 0);
  __syncthreads();
#pragma unroll 2
  for (int kt = 0; kt < 16; kt++) {
    const int cur = kt & 1, nx = cur ^ 1;
    if (kt < 15) G2_STAGE(kt + 1, nx);
    G2_COMPUTE(cur);
    __syncthreads();
  }

  // acc -> raw LDS (raw = h @ W2, no bias yet; cols 92..95 are zero via W2T pad)
#pragma unroll
  for (int mf = 0; mf < 2; mf++) {
#pragma unroll
    for (int nf = 0; nf < 3; nf++) {
#pragma unroll
      for (int r = 0; r < 4; r++) {
        const int ml = wr * 32 + mf * 16 + (lg << 2) + r;
        const int nl = wc * 48 + nf * 16 + l15;
        raw[ml][nl] = acc[mf][nf][r];
      }
    }
  }
  __syncthreads();

  const size_t OFFB = (size_t)BROWS * 72;   // offsets section
  const size_t LENB = (size_t)BROWS * 144;  // length section

  // phase 1: per (row, joint) -> direction*length, write offsets+length, off in-place
  for (int task = tid; task < 64 * 24; task += 256) {
    const int row = task / 24;
    const int j = task - row * 24;
    const int gm = m0 + row;
    float* orow = out + OFFB + (size_t)gm * 72;
    if (j == 0) {
      orow[0] = 0.0f; orow[1] = 0.0f; orow[2] = 0.0f;
    } else {
      const int c0 = (j - 1) * 4;
      const float vx = raw[row][c0 + 0] + b2[c0 + 0];
      const float vy = raw[row][c0 + 1] + b2[c0 + 1];
      const float vz = raw[row][c0 + 2] + b2[c0 + 2];
      const float wvv = raw[row][c0 + 3] + b2[c0 + 3];
      const float nrm = sqrtf(vx * vx + vy * vy + vz * vz);
      const float inv = 1.0f / fmaxf(nrm, 1e-12f);
      const float len = fmaxf(wvv, 0.0f) + log1pf(expf(-fabsf(wvv)));  // softplus
      const float sc = inv * len;
      const float ox = vx * sc, oy = vy * sc, oz = vz * sc;
      orow[j * 3 + 0] = ox; orow[j * 3 + 1] = oy; orow[j * 3 + 2] = oz;
      out[LENB + (size_t)gm * 23 + (j - 1)] = len;
      raw[row][c0 + 0] = ox; raw[row][c0 + 1] = oy; raw[row][c0 + 2] = oz;
    }
  }
  __syncthreads();

  // phase 2: forward kinematics, one thread per row, fully static unroll
  if (tid < 64) {
    constexpr int PAR[24] = {-1, 0, 0, 0, 1, 2, 3, 4, 5, 6, 7, 8,
                             9, 9, 9, 12, 13, 14, 16, 17, 18, 19, 20, 21};
    const int gm = m0 + tid;
    float e[72];
    e[0] = 0.0f; e[1] = 0.0f; e[2] = 0.0f;
#pragma unroll
    for (int j = 1; j < 24; j++) {
      const int p = PAR[j];
      const int c0 = (j - 1) * 4;
      e[3 * j + 0] = e[3 * p + 0] + raw[tid][c0 + 0];
      e[3 * j + 1] = e[3 * p + 1] + raw[tid][c0 + 1];
      e[3 * j + 2] = e[3 * p + 2] + raw[tid][c0 + 2];
    }
    float4* jo = (float4*)(out + (size_t)gm * 72);
#pragma unroll
    for (int q = 0; q < 18; q++)
      jo[q] = make_float4(e[4 * q + 0], e[4 * q + 1], e[4 * q + 2], e[4 * q + 3]);
  }
}

extern "C" void kernel_launch(void* const* d_in, const int* in_sizes, int n_in,
                              void* d_out, int out_size, void* d_ws, size_t ws_size,
                              hipStream_t stream) {
  const float* z = (const float*)d_in[0];
  const float* W1 = (const float*)d_in[1];
  const float* b1 = (const float*)d_in[2];
  const float* W2 = (const float*)d_in[3];
  const float* b2 = (const float*)d_in[4];
  float* out = (float*)d_out;

  char* ws = (char*)d_ws;
  unsigned short* w1f = (unsigned short*)(ws);                                  // 2 MB
  unsigned short* w2h = (unsigned short*)(ws + (2 << 20));                      // 128 KB
  unsigned short* w2l = (unsigned short*)(ws + (2 << 20) + 131072);             // 128 KB
  unsigned short* hh = (unsigned short*)(ws + ((size_t)4 << 20));               // 32 MB
  unsigned short* hl = (unsigned short*)(ws + ((size_t)4 << 20) + ((size_t)32 << 20));  // 32 MB

  hipFuncSetAttribute((const void*)k_gemm1,
                      hipFuncAttributeMaxDynamicSharedMemorySize, 65536);

  hipLaunchKernelGGL(k_prep_w1f, dim3(512), dim3(256), 0, stream, W1, w1f);
  hipLaunchKernelGGL(k_prep_w2t, dim3(256), dim3(256), 0, stream, W2, w2h, w2l);
  hipLaunchKernelGGL(k_gemm1, dim3(1024), dim3(256), 65536, stream, z, w1f, b1, hh, hl);
  hipLaunchKernelGGL(k_gemm2, dim3(512), dim3(256), 0, stream, hh, hl, w2h, w2l, b2, out);
}